// Round 12
// baseline (214.058 us; speedup 1.0000x reference)
//
#include <hip/hip_runtime.h>
#include <hip/hip_bf16.h>

// SelfAttentionHead: B=4, S=4096, D=256, fp32 in/out.
// out = qp + softmax(tril_mul(qp kp^T / 16)) @ vp, masked entries enter softmax as 0.
// R12 = R8/R11 attention core + two-tile issue interleave (QKa,QKb,SMa,PVa,SMb,PVb: MFMA
// chains overlap softmax VALU), 2 barriers per 64 keys; scans read vptb (vpf eliminated).

typedef __bf16 bf16x8 __attribute__((ext_vector_type(8)));
typedef float f32x4 __attribute__((ext_vector_type(4)));
typedef float f32x16 __attribute__((ext_vector_type(16)));
typedef unsigned int u32x4 __attribute__((ext_vector_type(4)));

#define MASKV -3.0e38f

__device__ __forceinline__ unsigned short f2bf_u(float f) {
  unsigned u = __float_as_uint(f);
  u += 0x7fffu + ((u >> 16) & 1u);
  return (unsigned short)(u >> 16);
}
__device__ __forceinline__ float bf2f(unsigned u16) {
  return __uint_as_float(u16 << 16);
}
__device__ __forceinline__ unsigned short cvt_bf(float f) {
  return __builtin_bit_cast(unsigned short, (__bf16)f);
}

// ---------------- WT[j][k] = bf16(W[k][j]) ----------------
__global__ __launch_bounds__(256) void wt_kernel(
    const float* __restrict__ Wq, const float* __restrict__ Wk, const float* __restrict__ Wv,
    unsigned short* __restrict__ WTq, unsigned short* __restrict__ WTk, unsigned short* __restrict__ WTv) {
  int j = blockIdx.x & 255;
  int wsel = blockIdx.x >> 8;
  const float* W = wsel == 0 ? Wq : (wsel == 1 ? Wk : Wv);
  unsigned short* WT = wsel == 0 ? WTq : (wsel == 1 ? WTk : WTv);
  int k = threadIdx.x;
  WT[j * 256 + k] = f2bf_u(W[k * 256 + j]);
}

// ---------------- Fused projection GEMMs: grid (256, 3) ----------------
__global__ __launch_bounds__(256) void proj_all_kernel(
    const float* __restrict__ q_in, const float* __restrict__ k_in, const float* __restrict__ v_in,
    const unsigned short* __restrict__ WTq, const unsigned short* __restrict__ WTk,
    const unsigned short* __restrict__ WTv,
    const float* __restrict__ bq, const float* __restrict__ bk, const float* __restrict__ bv,
    unsigned short* __restrict__ qpb, unsigned short* __restrict__ kpb,
    unsigned short* __restrict__ vptb) {
  int mode = blockIdx.y;
  const float* X = mode == 0 ? q_in : (mode == 1 ? k_in : v_in);
  const unsigned short* WT = mode == 0 ? WTq : (mode == 1 ? WTk : WTv);
  const float* bias = mode == 0 ? bq : (mode == 1 ? bk : bv);

  int rt = blockIdx.x;
  int tid = threadIdx.x;
  int w = tid >> 6, l = tid & 63, g = l >> 4, lm = l & 15;
  int arow = rt * 64 + w * 16 + lm;

  f32x4 acc[16];
#pragma unroll
  for (int i = 0; i < 16; i++) acc[i] = (f32x4){0.f, 0.f, 0.f, 0.f};

#pragma unroll
  for (int kb = 0; kb < 256; kb += 32) {
    const float* ap = X + arow * 256 + kb + 8 * g;
    float4 a0 = *(const float4*)ap;
    float4 a1 = *(const float4*)(ap + 4);
    bf16x8 af;
    af[0] = (__bf16)a0.x; af[1] = (__bf16)a0.y; af[2] = (__bf16)a0.z; af[3] = (__bf16)a0.w;
    af[4] = (__bf16)a1.x; af[5] = (__bf16)a1.y; af[6] = (__bf16)a1.z; af[7] = (__bf16)a1.w;
#pragma unroll
    for (int nt = 0; nt < 16; nt++) {
      bf16x8 bf = *(const bf16x8*)(WT + (nt * 16 + lm) * 256 + kb + 8 * g);
      acc[nt] = __builtin_amdgcn_mfma_f32_16x16x32_bf16(af, bf, acc[nt], 0, 0, 0);
    }
  }

#pragma unroll
  for (int nt = 0; nt < 16; nt++) {
    int col = nt * 16 + lm;
    float bb = bias[col];
#pragma unroll
    for (int r = 0; r < 4; r++) {
      int orow = rt * 64 + w * 16 + 4 * g + r;
      float v = acc[nt][r] + bb;
      int idx = orow * 256 + col;
      if (mode == 0) {
        qpb[idx] = f2bf_u(v * 0.0625f);  // bf16(qp/16): lossless pow2, residual = 16*bf2f
      } else if (mode == 1) {
        kpb[idx] = f2bf_u(v * 1.4426950408889634f);  // fold log2e -> scores in log2 space
      } else {
        int b = orow >> 12, sidx = orow & 4095;
        vptb[(((size_t)b * 128 + (sidx >> 5)) * 256 + col) * 32 + (sidx & 31)] = f2bf_u(v);
      }
    }
  }
}

// ---------------- Suffix-sum of vp from vptb (bf16, tiled), 32-row chunks ----------------
__global__ __launch_bounds__(256) void scan1(const unsigned short* __restrict__ vptb,
                                             float* __restrict__ ctot) {
  int c = blockIdx.x, b = blockIdx.y, d = threadIdx.x;
  const unsigned short* base = vptb + (((size_t)b * 128 + c) * 256 + d) * 32;
  float acc = 0.f;
#pragma unroll
  for (int r = 0; r < 32; r++) acc += bf2f(base[r]);
  ctot[(b * 128 + c) * 256 + d] = acc;
}

__global__ __launch_bounds__(256) void scan2(const unsigned short* __restrict__ vptb,
                                             const float* __restrict__ ctot,
                                             unsigned short* __restrict__ suffv) {
  int c = blockIdx.x, b = blockIdx.y, d = threadIdx.x;
  float acc = 0.f;
  for (int c2 = c + 1; c2 < 128; c2++) acc += ctot[(b * 128 + c2) * 256 + d];
  const unsigned short* base = vptb + (((size_t)b * 128 + c) * 256 + d) * 32;
  unsigned short* sbase = suffv + ((size_t)b * 4096 + c * 32) * 256 + d;
  for (int r = 31; r >= 0; r--) {
    sbase[r * 256] = f2bf_u(acc);
    acc += bf2f(base[r]);
  }
}

// ---------------- Flash attention: two-tile interleaved epochs, double buffer ----------------
// 768 blocks x 4 waves (128 q-rows). bid&7: b=(bid&7)>>1, shi=bid&1 (k-half).
// j=bid>>3 in [0,96): qb = 31 - j/3 (big-first), s = shi*3 + j%3; k-tiles [s*NT/6,(s+1)*NT/6).
// LDS 64KB: 2 x (K[32][256] swz + Vt[256][32] swz). Epoch (2 tiles): vmcnt(0) bar |
// QKa QKb SMa PVa SMb PVb (MFMA chains overlap softmax VALU) | bar | STAGE(kt+2,kt+3).
__global__ __launch_bounds__(256, 2) void attn12_kernel(
    const unsigned short* __restrict__ qpb, const unsigned short* __restrict__ kpb,
    const unsigned short* __restrict__ vptb,
    unsigned short* __restrict__ slot01,  // d_out, row-interleaved [grow][s][256]
    unsigned short* __restrict__ slot23,  // [s-2][grow][256]
    unsigned short* __restrict__ slot45,  // [s-4][grow][256]
    float* __restrict__ mz) {             // [s][m/Z][16384]
  extern __shared__ char smem[];

  int bid = blockIdx.x;
  int low = bid & 7;
  int b = low >> 1, shi = low & 1;
  int j = bid >> 3;
  int jd3 = j / 3;
  int qb = 31 - jd3;
  int s = shi * 3 + (j - jd3 * 3);
  int NT = 4 * (qb + 1);
  int t0 = (s * NT) / 6, t1 = ((s + 1) * NT) / 6;

  int tid = threadIdx.x;
  int wv = tid >> 6, l = tid & 63;
  int hi = l >> 5, r32 = l & 31;
  int vsw = (r32 >> 1) & 3;  // V read swizzle
  int ksw = r32 & 7;         // K read swizzle

  int qwave = qb * 128 + 32 * wv;
  int qglob = qwave + r32;

  // Q as B-fragments (col = lane&31 = q-row), pre-scaled by 1/16 (log2e folded into K)
  bf16x8 qf[16];
  const unsigned short* qsrc = qpb + (size_t)(b * 4096 + qwave + r32) * 256;
#pragma unroll
  for (int st = 0; st < 16; st++) qf[st] = *(const bf16x8*)(qsrc + st * 16 + 8 * hi);

  f32x16 zero16;
#pragma unroll
  for (int ee = 0; ee < 16; ee++) zero16[ee] = 0.f;
  f32x16 O[8];
#pragma unroll
  for (int dt = 0; dt < 8; dt++) O[dt] = zero16;
  float m_ = -1e30f, Z_ = 0.f;

  const unsigned short* kbase0 = kpb + (size_t)b * 4096 * 256;
  const unsigned short* vbase0 = vptb + (size_t)b * 128 * 256 * 32;

  auto STAGE = [&](int bi, int kt) {
    char* Kdst = smem + bi * 16384;
    char* Vdst = smem + 32768 + bi * 16384;
    const unsigned short* ksrc = kbase0 + (size_t)kt * 32 * 256;
    const unsigned short* vtile = vbase0 + (size_t)kt * 256 * 32;
#pragma unroll
    for (int j2 = 0; j2 < 4; j2++) {
      int ch = wv * 4 + j2;
      int row = ch * 2 + (l >> 5);
      int cc = (l & 31) ^ (row & 7);
      __builtin_amdgcn_global_load_lds(
          (const __attribute__((address_space(1))) unsigned int*)(ksrc + row * 256 + cc * 8),
          (__attribute__((address_space(3))) unsigned int*)(Kdst + ch * 1024), 16, 0, 0);
    }
#pragma unroll
    for (int j2 = 0; j2 < 4; j2++) {
      int ch = wv * 4 + j2;
      int d = ch * 16 + (l >> 2);
      int cc = (l & 3) ^ ((l >> 3) & 3);
      __builtin_amdgcn_global_load_lds(
          (const __attribute__((address_space(1))) unsigned int*)(vtile + d * 32 + cc * 8),
          (__attribute__((address_space(3))) unsigned int*)(Vdst + ch * 1024), 16, 0, 0);
    }
  };

  // QK^T (swapped) from buffer bi into St (log2-space scores)
  auto QK = [&](int bi, f32x16& St) {
    const char* Kp = smem + bi * 16384;
    __builtin_amdgcn_s_setprio(1);
    {
      bf16x8 kf = *(const bf16x8*)(Kp + r32 * 512 + ((hi ^ ksw) * 16));
      St = __builtin_amdgcn_mfma_f32_32x32x16_bf16(kf, qf[0], zero16, 0, 0, 0);
    }
#pragma unroll
    for (int st = 1; st < 16; st++) {
      bf16x8 kf = *(const bf16x8*)(Kp + r32 * 512 + (((2 * st + hi) ^ ksw) * 16));
      St = __builtin_amdgcn_mfma_f32_32x32x16_bf16(kf, qf[st], St, 0, 0, 0);
    }
    __builtin_amdgcn_s_setprio(0);
  };

  // mask + online softmax + pack + PV for tile at kb2 from buffer bi
  auto SMPV = [&](int bi, int kb2, f32x16& St) {
    const char* Vp = smem + 32768 + bi * 16384;

    if (kb2 + 31 > qwave) {
#pragma unroll
      for (int r = 0; r < 16; r++) {
        int kg = kb2 + (r & 3) + 8 * (r >> 2) + 4 * hi;
        if (kg > qglob) St[r] = MASKV;
      }
    }

    float mx = fmaxf(fmaxf(fmaxf(St[0], St[1]), fmaxf(St[2], St[3])),
                     fmaxf(fmaxf(St[4], St[5]), fmaxf(St[6], St[7])));
    float mx2 = fmaxf(fmaxf(fmaxf(St[8], St[9]), fmaxf(St[10], St[11])),
                      fmaxf(fmaxf(St[12], St[13]), fmaxf(St[14], St[15])));
    mx = fmaxf(mx, mx2);
    mx = fmaxf(mx, __shfl_xor(mx, 32));
    bool upd = __any(mx > m_ + 8.f);
    if (upd) {
      float mn = fmaxf(m_, mx);
      float scl = exp2f(m_ - mn);
      m_ = mn;
      Z_ *= scl;
#pragma unroll
      for (int r = 0; r < 16; r++) {
        int qr = (r & 3) + 8 * (r >> 2) + 4 * hi;
        float sb = __uint_as_float(
            (unsigned)__builtin_amdgcn_ds_bpermute(qr * 4, (int)__float_as_uint(scl)));
#pragma unroll
        for (int dt = 0; dt < 8; dt++) O[dt][r] *= sb;
      }
    }
    float p[16];
#pragma unroll
    for (int r = 0; r < 16; r++) p[r] = exp2f(St[r] - m_);
    float rs = ((p[0] + p[1]) + (p[2] + p[3])) + ((p[4] + p[5]) + (p[6] + p[7])) +
               (((p[8] + p[9]) + (p[10] + p[11])) + ((p[12] + p[13]) + (p[14] + p[15])));
    rs += __shfl_xor(rs, 32);
    Z_ += rs;

    unsigned X[8];
#pragma unroll
    for (int i = 0; i < 8; i++)
      X[i] = (unsigned)cvt_bf(p[2 * i]) | ((unsigned)cvt_bf(p[2 * i + 1]) << 16);
    unsigned Y0 = (unsigned)__shfl_xor((int)X[0], 32);
    unsigned Y1 = (unsigned)__shfl_xor((int)X[1], 32);
    unsigned Y2 = (unsigned)__shfl_xor((int)X[2], 32);
    unsigned Y3 = (unsigned)__shfl_xor((int)X[3], 32);
    unsigned Y4 = (unsigned)__shfl_xor((int)X[4], 32);
    unsigned Y5 = (unsigned)__shfl_xor((int)X[5], 32);
    unsigned Y6 = (unsigned)__shfl_xor((int)X[6], 32);
    unsigned Y7 = (unsigned)__shfl_xor((int)X[7], 32);
    u32x4 A0, A1;
    A0[0] = hi ? Y2 : X[0]; A0[1] = hi ? Y3 : X[1];
    A0[2] = hi ? X[2] : Y0; A0[3] = hi ? X[3] : Y1;
    A1[0] = hi ? Y6 : X[4]; A1[1] = hi ? Y7 : X[5];
    A1[2] = hi ? X[6] : Y4; A1[3] = hi ? X[7] : Y5;
    bf16x8 pa0 = __builtin_bit_cast(bf16x8, A0);
    bf16x8 pa1 = __builtin_bit_cast(bf16x8, A1);

    __builtin_amdgcn_s_setprio(1);
#pragma unroll
    for (int dt = 0; dt < 8; dt++) {
      bf16x8 vf0 = *(const bf16x8*)(Vp + (dt * 32 + r32) * 64 + ((hi ^ vsw) * 16));
      O[dt] = __builtin_amdgcn_mfma_f32_32x32x16_bf16(pa0, vf0, O[dt], 0, 0, 0);
    }
#pragma unroll
    for (int dt = 0; dt < 8; dt++) {
      bf16x8 vf1 = *(const bf16x8*)(Vp + (dt * 32 + r32) * 64 + (((2 + hi) ^ vsw) * 16));
      O[dt] = __builtin_amdgcn_mfma_f32_32x32x16_bf16(pa1, vf1, O[dt], 0, 0, 0);
    }
    __builtin_amdgcn_s_setprio(0);
  };

  if (t0 < t1) {
    STAGE(0, t0);
    if (t0 + 1 < t1) STAGE(1, t0 + 1);
  }

  for (int kt = t0; kt < t1; kt += 2) {
    bool hasB = (kt + 1 < t1);
    int kbA = kt * 32, kbB = (kt + 1) * 32;
    bool doA = (kbA <= qwave + 31);
    bool doB = hasB && (kbB <= qwave + 31);

    asm volatile("s_waitcnt vmcnt(0)" ::: "memory");
    __builtin_amdgcn_s_barrier();
    __builtin_amdgcn_sched_barrier(0);

    f32x16 Sa, Sb;
    if (doA) QK(0, Sa);
    if (doB) QK(1, Sb);   // B's MFMA chain drains while SMa's VALU runs
    if (doA) SMPV(0, kbA, Sa);
    if (doB) SMPV(1, kbB, Sb);

    __builtin_amdgcn_sched_barrier(0);
    __builtin_amdgcn_s_barrier();  // all waves done reading both buffers
    if (kt + 2 < t1) STAGE(0, kt + 2);
    if (kt + 3 < t1) STAGE(1, kt + 3);
  }

  // ---- write partial stats + bf16 O ----
  int grow_base = b * 4096 + qwave;
  if (hi == 0) {
    float* mzm = mz + s * 32768;
    mzm[grow_base + r32] = m_;
    mzm[16384 + grow_base + r32] = Z_;
  }
#pragma unroll
  for (int r = 0; r < 16; r++) {
    int qr = (r & 3) + 8 * (r >> 2) + 4 * hi;
    size_t grow = (size_t)(grow_base + qr);
#pragma unroll
    for (int dt = 0; dt < 8; dt++) {
      int dcol = dt * 32 + r32;
      unsigned short vb = cvt_bf(O[dt][r]);
      if (s < 2)
        slot01[grow * 512 + (size_t)s * 256 + dcol] = vb;
      else if (s < 4)
        slot23[(size_t)(s - 2) * 4194304 + grow * 256 + dcol] = vb;
      else
        slot45[(size_t)(s - 4) * 4194304 + grow * 256 + dcol] = vb;
    }
  }
}

// ---------------- combine6: merge 6 partials + masked-zero correction + qp residual ----------------
__global__ __launch_bounds__(256) void combine6_kernel(
    const float* __restrict__ mz,
    const unsigned short* __restrict__ slot23, const unsigned short* __restrict__ slot45,
    const unsigned short* __restrict__ qpb, const unsigned short* __restrict__ suffv,
    float* __restrict__ out) {
  int grow = blockIdx.x * 4 + (threadIdx.x >> 6);
  int col = (threadIdx.x & 63) * 4;
  const unsigned short* slot01 = (const unsigned short*)out;

  float mv[6], Zv[6];
#pragma unroll
  for (int s = 0; s < 6; s++) {
    const float* mzm = mz + s * 32768;
    mv[s] = mzm[grow];
    Zv[s] = mzm[16384 + grow];
  }
  float M = mv[0];
#pragma unroll
  for (int s = 1; s < 6; s++) M = fmaxf(M, mv[s]);
  float fs[6], Zm = 0.f;
#pragma unroll
  for (int s = 0; s < 6; s++) {
    fs[s] = exp2f(mv[s] - M);
    Zm += Zv[s] * fs[s];
  }

  int q = grow & 4095;
  int nmask = 4095 - q;
  float scl, e0, Zf;
  if (nmask > 0) {
    float Mf = fmaxf(M, 0.f);  // log2-space: masked zeros contribute 2^(0 - Mf)
    scl = exp2f(M - Mf);
    e0 = exp2f(-Mf);
    Zf = Zm * scl + (float)nmask * e0;
  } else {
    scl = 1.f; e0 = 0.f; Zf = Zm;
  }
  float rZ = 1.f / Zf;
  float a[6];
#pragma unroll
  for (int s = 0; s < 6; s++) a[s] = fs[s] * scl * rZ;
  float asv = e0 * rZ;

  size_t base = (size_t)grow * 256 + col;
  uint2 ss[6];
  ss[0] = *(const uint2*)(slot01 + (size_t)grow * 512 + col);
  ss[1] = *(const uint2*)(slot01 + (size_t)grow * 512 + 256 + col);
  ss[2] = *(const uint2*)(slot23 + base);
  ss[3] = *(const uint2*)(slot23 + 4194304 + base);
  ss[4] = *(const uint2*)(slot45 + base);
  ss[5] = *(const uint2*)(slot45 + 4194304 + base);
  uint2 qpr = *(const uint2*)(qpb + base);
  uint2 svu = *(const uint2*)(suffv + base);

  __syncthreads();  // all slot01 (= out bytes) reads in this block complete before writes

  float4 res;
  res.x = 16.f * bf2f(qpr.x & 0xffff) + bf2f(svu.x & 0xffff) * asv;
  res.y = 16.f * bf2f(qpr.x >> 16) + bf2f(svu.x >> 16) * asv;
  res.z = 16.f * bf2f(qpr.y & 0xffff) + bf2f(svu.y & 0xffff) * asv;
  res.w = 16.f * bf2f(qpr.y >> 16) + bf2f(svu.y >> 16) * asv;
#pragma unroll
  for (int s = 0; s < 6; s++) {
    res.x += bf2f(ss[s].x & 0xffff) * a[s];
    res.y += bf2f(ss[s].x >> 16) * a[s];
    res.z += bf2f(ss[s].y & 0xffff) * a[s];
    res.w += bf2f(ss[s].y >> 16) * a[s];
  }
  *(float4*)&out[base] = res;
}

// ---------------- launch ----------------
// Workspace layout (disjoint; ~66 MiB, within proven bound):
//   [ 0,16M) slot45 | [16M,32M) slot23 | [32M,40M) suffv bf16 | [40M,48M) qpb
//   [48M,56M) kpb | [56M,64M) vptb [B][128][256][32] | [64M,+768K) mz | +384K WT | +512K ctot
extern "C" void kernel_launch(void* const* d_in, const int* in_sizes, int n_in,
                              void* d_out, int out_size, void* d_ws, size_t ws_size,
                              hipStream_t stream) {
  const float* v_in = (const float*)d_in[0];
  const float* k_in = (const float*)d_in[1];
  const float* q_in = (const float*)d_in[2];
  const float* Wq = (const float*)d_in[3];
  const float* bq = (const float*)d_in[4];
  const float* Wk = (const float*)d_in[5];
  const float* bk = (const float*)d_in[6];
  const float* Wv = (const float*)d_in[7];
  const float* bv = (const float*)d_in[8];
  float* out = (float*)d_out;

  char* p = (char*)d_ws;
  unsigned short* slot45 = (unsigned short*)(p + 0);
  unsigned short* slot23 = (unsigned short*)(p + 16777216);
  unsigned short* suffv = (unsigned short*)(p + 33554432);
  unsigned short* qpb = (unsigned short*)(p + 41943040);
  unsigned short* kpb = (unsigned short*)(p + 50331648);
  unsigned short* vptb = (unsigned short*)(p + 58720256);
  float* mz = (float*)(p + 67108864);
  unsigned short* WTq = (unsigned short*)(p + 67895296);
  unsigned short* WTk = (unsigned short*)(p + 68026368);
  unsigned short* WTv = (unsigned short*)(p + 68157440);
  float* ctot = (float*)(p + 68288512);                 // [4][128][256] f32 = 512 KB
  unsigned short* slot01 = (unsigned short*)d_out;

  hipFuncSetAttribute((const void*)attn12_kernel,
                      hipFuncAttributeMaxDynamicSharedMemorySize, 65536);

  wt_kernel<<<768, 256, 0, stream>>>(Wq, Wk, Wv, WTq, WTk, WTv);
  proj_all_kernel<<<dim3(256, 3), 256, 0, stream>>>(q_in, k_in, v_in, WTq, WTk, WTv,
                                                    bq, bk, bv, qpb, kpb, vptb);
  scan1<<<dim3(128, 4), 256, 0, stream>>>(vptb, ctot);
  scan2<<<dim3(128, 4), 256, 0, stream>>>(vptb, ctot, suffv);
  attn12_kernel<<<768, 256, 65536, stream>>>(qpb, kpb, vptb, slot01, slot23, slot45, mz);
  combine6_kernel<<<4096, 256, 0, stream>>>(mz, slot23, slot45, qpb, suffv, out);
}

// Round 13
// 187.278 us; speedup vs baseline: 1.1430x; 1.1430x over previous
//
#include <hip/hip_runtime.h>
#include <hip/hip_bf16.h>

// SelfAttentionHead: B=4, S=4096, D=256, fp32 in/out.
// out = qp + softmax(tril_mul(qp kp^T / 16)) @ vp, masked entries enter softmax as 0.
// R13 = R8 attention core EXACTLY (best measured: 99us) + vpf-less proj/scans (R12's
// orthogonal win). Uniform-6 split-K, exp2 softmax, counted-vmcnt dbuf, combine6.

typedef __bf16 bf16x8 __attribute__((ext_vector_type(8)));
typedef float f32x4 __attribute__((ext_vector_type(4)));
typedef float f32x16 __attribute__((ext_vector_type(16)));
typedef unsigned int u32x4 __attribute__((ext_vector_type(4)));

#define MASKV -3.0e38f

__device__ __forceinline__ unsigned short f2bf_u(float f) {
  unsigned u = __float_as_uint(f);
  u += 0x7fffu + ((u >> 16) & 1u);
  return (unsigned short)(u >> 16);
}
__device__ __forceinline__ float bf2f(unsigned u16) {
  return __uint_as_float(u16 << 16);
}
__device__ __forceinline__ unsigned short cvt_bf(float f) {
  return __builtin_bit_cast(unsigned short, (__bf16)f);
}

// ---------------- WT[j][k] = bf16(W[k][j]) ----------------
__global__ __launch_bounds__(256) void wt_kernel(
    const float* __restrict__ Wq, const float* __restrict__ Wk, const float* __restrict__ Wv,
    unsigned short* __restrict__ WTq, unsigned short* __restrict__ WTk, unsigned short* __restrict__ WTv) {
  int j = blockIdx.x & 255;
  int wsel = blockIdx.x >> 8;
  const float* W = wsel == 0 ? Wq : (wsel == 1 ? Wk : Wv);
  unsigned short* WT = wsel == 0 ? WTq : (wsel == 1 ? WTk : WTv);
  int k = threadIdx.x;
  WT[j * 256 + k] = f2bf_u(W[k * 256 + j]);
}

// ---------------- Fused projection GEMMs: grid (256, 3) ----------------
__global__ __launch_bounds__(256) void proj_all_kernel(
    const float* __restrict__ q_in, const float* __restrict__ k_in, const float* __restrict__ v_in,
    const unsigned short* __restrict__ WTq, const unsigned short* __restrict__ WTk,
    const unsigned short* __restrict__ WTv,
    const float* __restrict__ bq, const float* __restrict__ bk, const float* __restrict__ bv,
    unsigned short* __restrict__ qpb, unsigned short* __restrict__ kpb,
    unsigned short* __restrict__ vptb) {
  int mode = blockIdx.y;
  const float* X = mode == 0 ? q_in : (mode == 1 ? k_in : v_in);
  const unsigned short* WT = mode == 0 ? WTq : (mode == 1 ? WTk : WTv);
  const float* bias = mode == 0 ? bq : (mode == 1 ? bk : bv);

  int rt = blockIdx.x;
  int tid = threadIdx.x;
  int w = tid >> 6, l = tid & 63, g = l >> 4, lm = l & 15;
  int arow = rt * 64 + w * 16 + lm;

  f32x4 acc[16];
#pragma unroll
  for (int i = 0; i < 16; i++) acc[i] = (f32x4){0.f, 0.f, 0.f, 0.f};

#pragma unroll
  for (int kb = 0; kb < 256; kb += 32) {
    const float* ap = X + arow * 256 + kb + 8 * g;
    float4 a0 = *(const float4*)ap;
    float4 a1 = *(const float4*)(ap + 4);
    bf16x8 af;
    af[0] = (__bf16)a0.x; af[1] = (__bf16)a0.y; af[2] = (__bf16)a0.z; af[3] = (__bf16)a0.w;
    af[4] = (__bf16)a1.x; af[5] = (__bf16)a1.y; af[6] = (__bf16)a1.z; af[7] = (__bf16)a1.w;
#pragma unroll
    for (int nt = 0; nt < 16; nt++) {
      bf16x8 bf = *(const bf16x8*)(WT + (nt * 16 + lm) * 256 + kb + 8 * g);
      acc[nt] = __builtin_amdgcn_mfma_f32_16x16x32_bf16(af, bf, acc[nt], 0, 0, 0);
    }
  }

#pragma unroll
  for (int nt = 0; nt < 16; nt++) {
    int col = nt * 16 + lm;
    float bb = bias[col];
#pragma unroll
    for (int r = 0; r < 4; r++) {
      int orow = rt * 64 + w * 16 + 4 * g + r;
      float v = acc[nt][r] + bb;
      int idx = orow * 256 + col;
      if (mode == 0) {
        qpb[idx] = f2bf_u(v * 0.0625f);  // bf16(qp/16): lossless pow2, residual = 16*bf2f
      } else if (mode == 1) {
        kpb[idx] = f2bf_u(v * 1.4426950408889634f);  // fold log2e -> scores in log2 space
      } else {
        int b = orow >> 12, sidx = orow & 4095;
        vptb[(((size_t)b * 128 + (sidx >> 5)) * 256 + col) * 32 + (sidx & 31)] = f2bf_u(v);
      }
    }
  }
}

// ---------------- Suffix-sum of vp from vptb (bf16, tiled), 32-row chunks ----------------
__global__ __launch_bounds__(256) void scan1(const unsigned short* __restrict__ vptb,
                                             float* __restrict__ ctot) {
  int c = blockIdx.x, b = blockIdx.y, d = threadIdx.x;
  const unsigned short* base = vptb + (((size_t)b * 128 + c) * 256 + d) * 32;
  float acc = 0.f;
#pragma unroll
  for (int r = 0; r < 32; r++) acc += bf2f(base[r]);
  ctot[(b * 128 + c) * 256 + d] = acc;
}

__global__ __launch_bounds__(256) void scan2(const unsigned short* __restrict__ vptb,
                                             const float* __restrict__ ctot,
                                             unsigned short* __restrict__ suffv) {
  int c = blockIdx.x, b = blockIdx.y, d = threadIdx.x;
  float acc = 0.f;
  for (int c2 = c + 1; c2 < 128; c2++) acc += ctot[(b * 128 + c2) * 256 + d];
  const unsigned short* base = vptb + (((size_t)b * 128 + c) * 256 + d) * 32;
  unsigned short* sbase = suffv + ((size_t)b * 4096 + c * 32) * 256 + d;
  for (int r = 31; r >= 0; r--) {
    sbase[r * 256] = f2bf_u(acc);
    acc += bf2f(base[r]);
  }
}

// ---------------- Flash attention: uniform-6 split-K, counted-vmcnt pipeline (R8) ----------------
// 768 blocks x 4 waves (128 q-rows). bid&7: b=(bid&7)>>1, shi=bid&1 (k-half: s in 0..2 / 3..5).
// j=bid>>3 in [0,96): qb = 31 - j/3 (descending -> big-first), s = shi*3 + j%3.
// k-tiles [s*NT/6, (s+1)*NT/6), NT = 4(qb+1). 2 blocks/CU resident + deep queue (refill).
__global__ __launch_bounds__(256, 2) void attn13_kernel(
    const unsigned short* __restrict__ qpb, const unsigned short* __restrict__ kpb,
    const unsigned short* __restrict__ vptb,
    unsigned short* __restrict__ slot01,  // d_out, row-interleaved [grow][s][256]
    unsigned short* __restrict__ slot23,  // [s-2][grow][256]
    unsigned short* __restrict__ slot45,  // [s-4][grow][256]
    float* __restrict__ mz) {             // [s][m/Z][16384]
  extern __shared__ char smem[];

  int bid = blockIdx.x;
  int low = bid & 7;
  int b = low >> 1, shi = low & 1;
  int j = bid >> 3;
  int jd3 = j / 3;
  int qb = 31 - jd3;
  int s = shi * 3 + (j - jd3 * 3);
  int NT = 4 * (qb + 1);
  int t0 = (s * NT) / 6, t1 = ((s + 1) * NT) / 6;

  int tid = threadIdx.x;
  int wv = tid >> 6, l = tid & 63;
  int hi = l >> 5, r32 = l & 31;
  int vsw = (r32 >> 1) & 3;  // V read swizzle
  int ksw = r32 & 7;         // K read swizzle

  int qwave = qb * 128 + 32 * wv;
  int qglob = qwave + r32;

  // Q as B-fragments (col = lane&31 = q-row), pre-scaled by 1/16 (log2e folded into K)
  bf16x8 qf[16];
  const unsigned short* qsrc = qpb + (size_t)(b * 4096 + qwave + r32) * 256;
#pragma unroll
  for (int st = 0; st < 16; st++) qf[st] = *(const bf16x8*)(qsrc + st * 16 + 8 * hi);

  f32x16 zero16;
#pragma unroll
  for (int ee = 0; ee < 16; ee++) zero16[ee] = 0.f;
  f32x16 O[8];
#pragma unroll
  for (int dt = 0; dt < 8; dt++) O[dt] = zero16;
  float m_ = -1e30f, Z_ = 0.f;

  const unsigned short* kbase0 = kpb + (size_t)b * 4096 * 256;
  const unsigned short* vbase0 = vptb + (size_t)b * 128 * 256 * 32;

  auto STAGE = [&](int bi, int kt) {
    char* Kdst = smem + bi * 16384;
    char* Vdst = smem + 32768 + bi * 16384;
    const unsigned short* ksrc = kbase0 + (size_t)kt * 32 * 256;
    const unsigned short* vtile = vbase0 + (size_t)kt * 256 * 32;
#pragma unroll
    for (int j2 = 0; j2 < 4; j2++) {
      int ch = wv * 4 + j2;
      int row = ch * 2 + (l >> 5);
      int cc = (l & 31) ^ (row & 7);
      __builtin_amdgcn_global_load_lds(
          (const __attribute__((address_space(1))) unsigned int*)(ksrc + row * 256 + cc * 8),
          (__attribute__((address_space(3))) unsigned int*)(Kdst + ch * 1024), 16, 0, 0);
    }
#pragma unroll
    for (int j2 = 0; j2 < 4; j2++) {
      int ch = wv * 4 + j2;
      int d = ch * 16 + (l >> 2);
      int cc = (l & 3) ^ ((l >> 3) & 3);
      __builtin_amdgcn_global_load_lds(
          (const __attribute__((address_space(1))) unsigned int*)(vtile + d * 32 + cc * 8),
          (__attribute__((address_space(3))) unsigned int*)(Vdst + ch * 1024), 16, 0, 0);
    }
  };

  if (t0 < t1) {
    STAGE(0, t0);
    if (t0 + 1 < t1) STAGE(1, t0 + 1);
  }

  for (int kt = t0; kt < t1; kt++) {
    int cur = (kt - t0) & 1;
    int kb2 = kt * 32;

    if (kt + 1 < t1) asm volatile("s_waitcnt vmcnt(8)" ::: "memory");
    else             asm volatile("s_waitcnt vmcnt(0)" ::: "memory");
    __builtin_amdgcn_s_barrier();
    __builtin_amdgcn_sched_barrier(0);

    if (kb2 <= qwave + 31) {  // wave not fully masked
      const char* Kp = smem + cur * 16384;
      const char* Vp = smem + 32768 + cur * 16384;

      // ---- QK^T (swapped): St[key][q] in log2-space, A=K frag from LDS, B=Q frag ----
      f32x16 St;
      __builtin_amdgcn_s_setprio(1);
      {
        bf16x8 kf = *(const bf16x8*)(Kp + r32 * 512 + ((hi ^ ksw) * 16));
        St = __builtin_amdgcn_mfma_f32_32x32x16_bf16(kf, qf[0], zero16, 0, 0, 0);
      }
#pragma unroll
      for (int st = 1; st < 16; st++) {
        bf16x8 kf = *(const bf16x8*)(Kp + r32 * 512 + (((2 * st + hi) ^ ksw) * 16));
        St = __builtin_amdgcn_mfma_f32_32x32x16_bf16(kf, qf[st], St, 0, 0, 0);
      }
      __builtin_amdgcn_s_setprio(0);

      // ---- causal mask (wave-uniform guard: only diagonal-crossing tiles) ----
      if (kb2 + 31 > qwave) {
#pragma unroll
        for (int r = 0; r < 16; r++) {
          int kg = kb2 + (r & 3) + 8 * (r >> 2) + 4 * hi;
          if (kg > qglob) St[r] = MASKV;
        }
      }

      // ---- in-register online softmax (exp2 space; row = this lane's q) ----
      float mx = fmaxf(fmaxf(fmaxf(St[0], St[1]), fmaxf(St[2], St[3])),
                       fmaxf(fmaxf(St[4], St[5]), fmaxf(St[6], St[7])));
      float mx2 = fmaxf(fmaxf(fmaxf(St[8], St[9]), fmaxf(St[10], St[11])),
                        fmaxf(fmaxf(St[12], St[13]), fmaxf(St[14], St[15])));
      mx = fmaxf(mx, mx2);
      mx = fmaxf(mx, __shfl_xor(mx, 32));
      bool upd = __any(mx > m_ + 8.f);
      if (upd) {
        float mn = fmaxf(m_, mx);
        float scl = exp2f(m_ - mn);
        m_ = mn;
        Z_ *= scl;
#pragma unroll
        for (int r = 0; r < 16; r++) {
          int qr = (r & 3) + 8 * (r >> 2) + 4 * hi;
          float sb = __uint_as_float(
              (unsigned)__builtin_amdgcn_ds_bpermute(qr * 4, (int)__float_as_uint(scl)));
#pragma unroll
          for (int dt = 0; dt < 8; dt++) O[dt][r] *= sb;
        }
      }
      float p[16];
#pragma unroll
      for (int r = 0; r < 16; r++) p[r] = exp2f(St[r] - m_);
      float rs = ((p[0] + p[1]) + (p[2] + p[3])) + ((p[4] + p[5]) + (p[6] + p[7])) +
                 (((p[8] + p[9]) + (p[10] + p[11])) + ((p[12] + p[13]) + (p[14] + p[15])));
      rs += __shfl_xor(rs, 32);
      Z_ += rs;

      // ---- P -> bf16 A-fragments (pack pairs + cross-half exchange) ----
      unsigned X[8];
#pragma unroll
      for (int i = 0; i < 8; i++)
        X[i] = (unsigned)cvt_bf(p[2 * i]) | ((unsigned)cvt_bf(p[2 * i + 1]) << 16);
      unsigned Y0 = (unsigned)__shfl_xor((int)X[0], 32);
      unsigned Y1 = (unsigned)__shfl_xor((int)X[1], 32);
      unsigned Y2 = (unsigned)__shfl_xor((int)X[2], 32);
      unsigned Y3 = (unsigned)__shfl_xor((int)X[3], 32);
      unsigned Y4 = (unsigned)__shfl_xor((int)X[4], 32);
      unsigned Y5 = (unsigned)__shfl_xor((int)X[5], 32);
      unsigned Y6 = (unsigned)__shfl_xor((int)X[6], 32);
      unsigned Y7 = (unsigned)__shfl_xor((int)X[7], 32);
      u32x4 A0, A1;
      A0[0] = hi ? Y2 : X[0]; A0[1] = hi ? Y3 : X[1];
      A0[2] = hi ? X[2] : Y0; A0[3] = hi ? X[3] : Y1;
      A1[0] = hi ? Y6 : X[4]; A1[1] = hi ? Y7 : X[5];
      A1[2] = hi ? X[6] : Y4; A1[3] = hi ? X[7] : Y5;
      bf16x8 pa0 = __builtin_bit_cast(bf16x8, A0);
      bf16x8 pa1 = __builtin_bit_cast(bf16x8, A1);

      // ---- PV: O[q][d] += P @ V ----
      __builtin_amdgcn_s_setprio(1);
#pragma unroll
      for (int dt = 0; dt < 8; dt++) {
        bf16x8 vf0 = *(const bf16x8*)(Vp + (dt * 32 + r32) * 64 + ((hi ^ vsw) * 16));
        O[dt] = __builtin_amdgcn_mfma_f32_32x32x16_bf16(pa0, vf0, O[dt], 0, 0, 0);
      }
#pragma unroll
      for (int dt = 0; dt < 8; dt++) {
        bf16x8 vf1 = *(const bf16x8*)(Vp + (dt * 32 + r32) * 64 + (((2 + hi) ^ vsw) * 16));
        O[dt] = __builtin_amdgcn_mfma_f32_32x32x16_bf16(pa1, vf1, O[dt], 0, 0, 0);
      }
      __builtin_amdgcn_s_setprio(0);
    }

    __builtin_amdgcn_sched_barrier(0);
    __builtin_amdgcn_s_barrier();
    if (kt + 2 < t1) STAGE(cur, kt + 2);
  }

  // ---- write partial stats + bf16 O ----
  int grow_base = b * 4096 + qwave;
  if (hi == 0) {
    float* mzm = mz + s * 32768;
    mzm[grow_base + r32] = m_;
    mzm[16384 + grow_base + r32] = Z_;
  }
#pragma unroll
  for (int r = 0; r < 16; r++) {
    int qr = (r & 3) + 8 * (r >> 2) + 4 * hi;
    size_t grow = (size_t)(grow_base + qr);
#pragma unroll
    for (int dt = 0; dt < 8; dt++) {
      int dcol = dt * 32 + r32;
      unsigned short vb = cvt_bf(O[dt][r]);
      if (s < 2)
        slot01[grow * 512 + (size_t)s * 256 + dcol] = vb;
      else if (s < 4)
        slot23[(size_t)(s - 2) * 4194304 + grow * 256 + dcol] = vb;
      else
        slot45[(size_t)(s - 4) * 4194304 + grow * 256 + dcol] = vb;
    }
  }
}

// ---------------- combine6: merge 6 partials + masked-zero correction + qp residual ----------------
__global__ __launch_bounds__(256) void combine6_kernel(
    const float* __restrict__ mz,
    const unsigned short* __restrict__ slot23, const unsigned short* __restrict__ slot45,
    const unsigned short* __restrict__ qpb, const unsigned short* __restrict__ suffv,
    float* __restrict__ out) {
  int grow = blockIdx.x * 4 + (threadIdx.x >> 6);
  int col = (threadIdx.x & 63) * 4;
  const unsigned short* slot01 = (const unsigned short*)out;

  float mv[6], Zv[6];
#pragma unroll
  for (int s = 0; s < 6; s++) {
    const float* mzm = mz + s * 32768;
    mv[s] = mzm[grow];
    Zv[s] = mzm[16384 + grow];
  }
  float M = mv[0];
#pragma unroll
  for (int s = 1; s < 6; s++) M = fmaxf(M, mv[s]);
  float fs[6], Zm = 0.f;
#pragma unroll
  for (int s = 0; s < 6; s++) {
    fs[s] = exp2f(mv[s] - M);
    Zm += Zv[s] * fs[s];
  }

  int q = grow & 4095;
  int nmask = 4095 - q;
  float scl, e0, Zf;
  if (nmask > 0) {
    float Mf = fmaxf(M, 0.f);  // log2-space: masked zeros contribute 2^(0 - Mf)
    scl = exp2f(M - Mf);
    e0 = exp2f(-Mf);
    Zf = Zm * scl + (float)nmask * e0;
  } else {
    scl = 1.f; e0 = 0.f; Zf = Zm;
  }
  float rZ = 1.f / Zf;
  float a[6];
#pragma unroll
  for (int s = 0; s < 6; s++) a[s] = fs[s] * scl * rZ;
  float asv = e0 * rZ;

  size_t base = (size_t)grow * 256 + col;
  uint2 ss[6];
  ss[0] = *(const uint2*)(slot01 + (size_t)grow * 512 + col);
  ss[1] = *(const uint2*)(slot01 + (size_t)grow * 512 + 256 + col);
  ss[2] = *(const uint2*)(slot23 + base);
  ss[3] = *(const uint2*)(slot23 + 4194304 + base);
  ss[4] = *(const uint2*)(slot45 + base);
  ss[5] = *(const uint2*)(slot45 + 4194304 + base);
  uint2 qpr = *(const uint2*)(qpb + base);
  uint2 svu = *(const uint2*)(suffv + base);

  __syncthreads();  // all slot01 (= out bytes) reads in this block complete before writes

  float4 res;
  res.x = 16.f * bf2f(qpr.x & 0xffff) + bf2f(svu.x & 0xffff) * asv;
  res.y = 16.f * bf2f(qpr.x >> 16) + bf2f(svu.x >> 16) * asv;
  res.z = 16.f * bf2f(qpr.y & 0xffff) + bf2f(svu.y & 0xffff) * asv;
  res.w = 16.f * bf2f(qpr.y >> 16) + bf2f(svu.y >> 16) * asv;
#pragma unroll
  for (int s = 0; s < 6; s++) {
    res.x += bf2f(ss[s].x & 0xffff) * a[s];
    res.y += bf2f(ss[s].x >> 16) * a[s];
    res.z += bf2f(ss[s].y & 0xffff) * a[s];
    res.w += bf2f(ss[s].y >> 16) * a[s];
  }
  *(float4*)&out[base] = res;
}

// ---------------- launch ----------------
// Workspace layout (disjoint; ~66 MiB, within proven bound):
//   [ 0,16M) slot45 | [16M,32M) slot23 | [32M,40M) suffv bf16 | [40M,48M) qpb
//   [48M,56M) kpb | [56M,64M) vptb [B][128][256][32] | [64M,+768K) mz | +384K WT | +512K ctot
extern "C" void kernel_launch(void* const* d_in, const int* in_sizes, int n_in,
                              void* d_out, int out_size, void* d_ws, size_t ws_size,
                              hipStream_t stream) {
  const float* v_in = (const float*)d_in[0];
  const float* k_in = (const float*)d_in[1];
  const float* q_in = (const float*)d_in[2];
  const float* Wq = (const float*)d_in[3];
  const float* bq = (const float*)d_in[4];
  const float* Wk = (const float*)d_in[5];
  const float* bk = (const float*)d_in[6];
  const float* Wv = (const float*)d_in[7];
  const float* bv = (const float*)d_in[8];
  float* out = (float*)d_out;

  char* p = (char*)d_ws;
  unsigned short* slot45 = (unsigned short*)(p + 0);
  unsigned short* slot23 = (unsigned short*)(p + 16777216);
  unsigned short* suffv = (unsigned short*)(p + 33554432);
  unsigned short* qpb = (unsigned short*)(p + 41943040);
  unsigned short* kpb = (unsigned short*)(p + 50331648);
  unsigned short* vptb = (unsigned short*)(p + 58720256);
  float* mz = (float*)(p + 67108864);
  unsigned short* WTq = (unsigned short*)(p + 67895296);
  unsigned short* WTk = (unsigned short*)(p + 68026368);
  unsigned short* WTv = (unsigned short*)(p + 68157440);
  float* ctot = (float*)(p + 68288512);                 // [4][128][256] f32 = 512 KB
  unsigned short* slot01 = (unsigned short*)d_out;

  hipFuncSetAttribute((const void*)attn13_kernel,
                      hipFuncAttributeMaxDynamicSharedMemorySize, 65536);

  wt_kernel<<<768, 256, 0, stream>>>(Wq, Wk, Wv, WTq, WTk, WTv);
  proj_all_kernel<<<dim3(256, 3), 256, 0, stream>>>(q_in, k_in, v_in, WTq, WTk, WTv,
                                                    bq, bk, bv, qpb, kpb, vptb);
  scan1<<<dim3(128, 4), 256, 0, stream>>>(vptb, ctot);
  scan2<<<dim3(128, 4), 256, 0, stream>>>(vptb, ctot, suffv);
  attn13_kernel<<<768, 256, 65536, stream>>>(qpb, kpb, vptb, slot01, slot23, slot45, mz);
  combine6_kernel<<<4096, 256, 0, stream>>>(mz, slot23, slot45, qpb, suffv, out);
}

// Round 14
// 151.840 us; speedup vs baseline: 1.4098x; 1.2334x over previous
//
#include <hip/hip_runtime.h>
#include <hip/hip_bf16.h>

// SelfAttentionHead: B=4, S=4096, D=256, fp32 in/out.
// out = qp + softmax(tril_mul(qp kp^T / 16)) @ vp, masked entries enter softmax as 0.
// R14 = R13 (attn/scans/combine identical) + LDS-staged proj: WT k-slices double-buffered
// via global_load_lds (pre-swizzled source), cutting 295MB of L2 fragment re-reads.

typedef __bf16 bf16x8 __attribute__((ext_vector_type(8)));
typedef float f32x4 __attribute__((ext_vector_type(4)));
typedef float f32x16 __attribute__((ext_vector_type(16)));
typedef unsigned int u32x4 __attribute__((ext_vector_type(4)));

#define MASKV -3.0e38f

__device__ __forceinline__ unsigned short f2bf_u(float f) {
  unsigned u = __float_as_uint(f);
  u += 0x7fffu + ((u >> 16) & 1u);
  return (unsigned short)(u >> 16);
}
__device__ __forceinline__ float bf2f(unsigned u16) {
  return __uint_as_float(u16 << 16);
}
__device__ __forceinline__ unsigned short cvt_bf(float f) {
  return __builtin_bit_cast(unsigned short, (__bf16)f);
}

// ---------------- WT[j][k] = bf16(W[k][j]) ----------------
__global__ __launch_bounds__(256) void wt_kernel(
    const float* __restrict__ Wq, const float* __restrict__ Wk, const float* __restrict__ Wv,
    unsigned short* __restrict__ WTq, unsigned short* __restrict__ WTk, unsigned short* __restrict__ WTv) {
  int j = blockIdx.x & 255;
  int wsel = blockIdx.x >> 8;
  const float* W = wsel == 0 ? Wq : (wsel == 1 ? Wk : Wv);
  unsigned short* WT = wsel == 0 ? WTq : (wsel == 1 ? WTk : WTv);
  int k = threadIdx.x;
  WT[j * 256 + k] = f2bf_u(W[k * 256 + j]);
}

// ---------------- Fused projection GEMMs: grid (256, 3), LDS-staged B slices ----------------
// Per block: 64 rows x 256 cols, K=256 in 8 steps of 32. B-slice [256 col][32 k] bf16 = 16KB
// staged into LDS (double-buffered, global_load_lds w=16, source pre-swizzled cc^=col&3);
// each of 4 waves reads fragments from LDS instead of re-reading WT from L2 (4x less L2).
__global__ __launch_bounds__(256) void proj_all_kernel(
    const float* __restrict__ q_in, const float* __restrict__ k_in, const float* __restrict__ v_in,
    const unsigned short* __restrict__ WTq, const unsigned short* __restrict__ WTk,
    const unsigned short* __restrict__ WTv,
    const float* __restrict__ bq, const float* __restrict__ bk, const float* __restrict__ bv,
    unsigned short* __restrict__ qpb, unsigned short* __restrict__ kpb,
    unsigned short* __restrict__ vptb) {
  __shared__ char bsmem[32768];  // 2 x 16KB B-slice buffers

  int mode = blockIdx.y;
  const float* X = mode == 0 ? q_in : (mode == 1 ? k_in : v_in);
  const unsigned short* WT = mode == 0 ? WTq : (mode == 1 ? WTk : WTv);
  const float* bias = mode == 0 ? bq : (mode == 1 ? bk : bv);

  int rt = blockIdx.x;
  int tid = threadIdx.x;
  int w = tid >> 6, l = tid & 63, g = l >> 4, lm = l & 15;
  int arow = rt * 64 + w * 16 + lm;
  int lsw = lm & 3;  // B read swizzle (col&3 == lm&3 since col = nt*16+lm)

  f32x4 acc[16];
#pragma unroll
  for (int i = 0; i < 16; i++) acc[i] = (f32x4){0.f, 0.f, 0.f, 0.f};

  // stage B-slice for k-range [kb, kb+32) into buffer bi.
  // layout: chunk slot (col, cc) holds WT[col][kb + 8*(cc ^ (col&3)) .. +8]
  auto BSTAGE = [&](int bi, int kb) {
    char* dstbase = bsmem + bi * 16384 + w * 1024;
#pragma unroll
    for (int i = 0; i < 4; i++) {
      int chunkid = i * 256 + w * 64 + l;
      int col = chunkid >> 2, cc = chunkid & 3;
      const unsigned short* src = WT + col * 256 + kb + 8 * (cc ^ (col & 3));
      __builtin_amdgcn_global_load_lds(
          (const __attribute__((address_space(1))) unsigned int*)src,
          (__attribute__((address_space(3))) unsigned int*)(dstbase + i * 4096), 16, 0, 0);
    }
  };

  BSTAGE(0, 0);
  BSTAGE(1, 32);

  for (int kb8 = 0; kb8 < 8; kb8++) {
    int cur = kb8 & 1;
    int kb = kb8 * 32;

    if (kb8 + 1 < 8) asm volatile("s_waitcnt vmcnt(4)" ::: "memory");
    else             asm volatile("s_waitcnt vmcnt(0)" ::: "memory");
    __builtin_amdgcn_s_barrier();
    __builtin_amdgcn_sched_barrier(0);

    // A fragment (16 rows x 32 k per wave), cast fp32 -> bf16
    const float* ap = X + arow * 256 + kb + 8 * g;
    float4 a0 = *(const float4*)ap;
    float4 a1 = *(const float4*)(ap + 4);
    bf16x8 af;
    af[0] = (__bf16)a0.x; af[1] = (__bf16)a0.y; af[2] = (__bf16)a0.z; af[3] = (__bf16)a0.w;
    af[4] = (__bf16)a1.x; af[5] = (__bf16)a1.y; af[6] = (__bf16)a1.z; af[7] = (__bf16)a1.w;

    const char* Bs = bsmem + cur * 16384;
    __builtin_amdgcn_s_setprio(1);
#pragma unroll
    for (int nt = 0; nt < 16; nt++) {
      bf16x8 bf = *(const bf16x8*)(Bs + (nt * 16 + lm) * 64 + ((g ^ lsw) * 16));
      acc[nt] = __builtin_amdgcn_mfma_f32_16x16x32_bf16(af, bf, acc[nt], 0, 0, 0);
    }
    __builtin_amdgcn_s_setprio(0);

    __builtin_amdgcn_sched_barrier(0);
    __builtin_amdgcn_s_barrier();
    if (kb8 + 2 < 8) BSTAGE(cur, kb + 64);
  }

#pragma unroll
  for (int nt = 0; nt < 16; nt++) {
    int col = nt * 16 + lm;
    float bb = bias[col];
#pragma unroll
    for (int r = 0; r < 4; r++) {
      int orow = rt * 64 + w * 16 + 4 * g + r;
      float v = acc[nt][r] + bb;
      int idx = orow * 256 + col;
      if (mode == 0) {
        qpb[idx] = f2bf_u(v * 0.0625f);  // bf16(qp/16): lossless pow2, residual = 16*bf2f
      } else if (mode == 1) {
        kpb[idx] = f2bf_u(v * 1.4426950408889634f);  // fold log2e -> scores in log2 space
      } else {
        int b = orow >> 12, sidx = orow & 4095;
        vptb[(((size_t)b * 128 + (sidx >> 5)) * 256 + col) * 32 + (sidx & 31)] = f2bf_u(v);
      }
    }
  }
}

// ---------------- Suffix-sum of vp from vptb (bf16, tiled), 32-row chunks ----------------
__global__ __launch_bounds__(256) void scan1(const unsigned short* __restrict__ vptb,
                                             float* __restrict__ ctot) {
  int c = blockIdx.x, b = blockIdx.y, d = threadIdx.x;
  const unsigned short* base = vptb + (((size_t)b * 128 + c) * 256 + d) * 32;
  float acc = 0.f;
#pragma unroll
  for (int r = 0; r < 32; r++) acc += bf2f(base[r]);
  ctot[(b * 128 + c) * 256 + d] = acc;
}

__global__ __launch_bounds__(256) void scan2(const unsigned short* __restrict__ vptb,
                                             const float* __restrict__ ctot,
                                             unsigned short* __restrict__ suffv) {
  int c = blockIdx.x, b = blockIdx.y, d = threadIdx.x;
  float acc = 0.f;
  for (int c2 = c + 1; c2 < 128; c2++) acc += ctot[(b * 128 + c2) * 256 + d];
  const unsigned short* base = vptb + (((size_t)b * 128 + c) * 256 + d) * 32;
  unsigned short* sbase = suffv + ((size_t)b * 4096 + c * 32) * 256 + d;
  for (int r = 31; r >= 0; r--) {
    sbase[r * 256] = f2bf_u(acc);
    acc += bf2f(base[r]);
  }
}

// ---------------- Flash attention: uniform-6 split-K, counted-vmcnt pipeline (R8) ----------------
// 768 blocks x 4 waves (128 q-rows). bid&7: b=(bid&7)>>1, shi=bid&1 (k-half: s in 0..2 / 3..5).
// j=bid>>3 in [0,96): qb = 31 - j/3 (descending -> big-first), s = shi*3 + j%3.
// k-tiles [s*NT/6, (s+1)*NT/6), NT = 4(qb+1). 2 blocks/CU resident + deep queue (refill).
__global__ __launch_bounds__(256, 2) void attn14_kernel(
    const unsigned short* __restrict__ qpb, const unsigned short* __restrict__ kpb,
    const unsigned short* __restrict__ vptb,
    unsigned short* __restrict__ slot01,  // d_out, row-interleaved [grow][s][256]
    unsigned short* __restrict__ slot23,  // [s-2][grow][256]
    unsigned short* __restrict__ slot45,  // [s-4][grow][256]
    float* __restrict__ mz) {             // [s][m/Z][16384]
  extern __shared__ char smem[];

  int bid = blockIdx.x;
  int low = bid & 7;
  int b = low >> 1, shi = low & 1;
  int j = bid >> 3;
  int jd3 = j / 3;
  int qb = 31 - jd3;
  int s = shi * 3 + (j - jd3 * 3);
  int NT = 4 * (qb + 1);
  int t0 = (s * NT) / 6, t1 = ((s + 1) * NT) / 6;

  int tid = threadIdx.x;
  int wv = tid >> 6, l = tid & 63;
  int hi = l >> 5, r32 = l & 31;
  int vsw = (r32 >> 1) & 3;  // V read swizzle
  int ksw = r32 & 7;         // K read swizzle

  int qwave = qb * 128 + 32 * wv;
  int qglob = qwave + r32;

  // Q as B-fragments (col = lane&31 = q-row), pre-scaled by 1/16 (log2e folded into K)
  bf16x8 qf[16];
  const unsigned short* qsrc = qpb + (size_t)(b * 4096 + qwave + r32) * 256;
#pragma unroll
  for (int st = 0; st < 16; st++) qf[st] = *(const bf16x8*)(qsrc + st * 16 + 8 * hi);

  f32x16 zero16;
#pragma unroll
  for (int ee = 0; ee < 16; ee++) zero16[ee] = 0.f;
  f32x16 O[8];
#pragma unroll
  for (int dt = 0; dt < 8; dt++) O[dt] = zero16;
  float m_ = -1e30f, Z_ = 0.f;

  const unsigned short* kbase0 = kpb + (size_t)b * 4096 * 256;
  const unsigned short* vbase0 = vptb + (size_t)b * 128 * 256 * 32;

  auto STAGE = [&](int bi, int kt) {
    char* Kdst = smem + bi * 16384;
    char* Vdst = smem + 32768 + bi * 16384;
    const unsigned short* ksrc = kbase0 + (size_t)kt * 32 * 256;
    const unsigned short* vtile = vbase0 + (size_t)kt * 256 * 32;
#pragma unroll
    for (int j2 = 0; j2 < 4; j2++) {
      int ch = wv * 4 + j2;
      int row = ch * 2 + (l >> 5);
      int cc = (l & 31) ^ (row & 7);
      __builtin_amdgcn_global_load_lds(
          (const __attribute__((address_space(1))) unsigned int*)(ksrc + row * 256 + cc * 8),
          (__attribute__((address_space(3))) unsigned int*)(Kdst + ch * 1024), 16, 0, 0);
    }
#pragma unroll
    for (int j2 = 0; j2 < 4; j2++) {
      int ch = wv * 4 + j2;
      int d = ch * 16 + (l >> 2);
      int cc = (l & 3) ^ ((l >> 3) & 3);
      __builtin_amdgcn_global_load_lds(
          (const __attribute__((address_space(1))) unsigned int*)(vtile + d * 32 + cc * 8),
          (__attribute__((address_space(3))) unsigned int*)(Vdst + ch * 1024), 16, 0, 0);
    }
  };

  if (t0 < t1) {
    STAGE(0, t0);
    if (t0 + 1 < t1) STAGE(1, t0 + 1);
  }

  for (int kt = t0; kt < t1; kt++) {
    int cur = (kt - t0) & 1;
    int kb2 = kt * 32;

    if (kt + 1 < t1) asm volatile("s_waitcnt vmcnt(8)" ::: "memory");
    else             asm volatile("s_waitcnt vmcnt(0)" ::: "memory");
    __builtin_amdgcn_s_barrier();
    __builtin_amdgcn_sched_barrier(0);

    if (kb2 <= qwave + 31) {  // wave not fully masked
      const char* Kp = smem + cur * 16384;
      const char* Vp = smem + 32768 + cur * 16384;

      // ---- QK^T (swapped): St[key][q] in log2-space, A=K frag from LDS, B=Q frag ----
      f32x16 St;
      __builtin_amdgcn_s_setprio(1);
      {
        bf16x8 kf = *(const bf16x8*)(Kp + r32 * 512 + ((hi ^ ksw) * 16));
        St = __builtin_amdgcn_mfma_f32_32x32x16_bf16(kf, qf[0], zero16, 0, 0, 0);
      }
#pragma unroll
      for (int st = 1; st < 16; st++) {
        bf16x8 kf = *(const bf16x8*)(Kp + r32 * 512 + (((2 * st + hi) ^ ksw) * 16));
        St = __builtin_amdgcn_mfma_f32_32x32x16_bf16(kf, qf[st], St, 0, 0, 0);
      }
      __builtin_amdgcn_s_setprio(0);

      // ---- causal mask (wave-uniform guard: only diagonal-crossing tiles) ----
      if (kb2 + 31 > qwave) {
#pragma unroll
        for (int r = 0; r < 16; r++) {
          int kg = kb2 + (r & 3) + 8 * (r >> 2) + 4 * hi;
          if (kg > qglob) St[r] = MASKV;
        }
      }

      // ---- in-register online softmax (exp2 space; row = this lane's q) ----
      float mx = fmaxf(fmaxf(fmaxf(St[0], St[1]), fmaxf(St[2], St[3])),
                       fmaxf(fmaxf(St[4], St[5]), fmaxf(St[6], St[7])));
      float mx2 = fmaxf(fmaxf(fmaxf(St[8], St[9]), fmaxf(St[10], St[11])),
                        fmaxf(fmaxf(St[12], St[13]), fmaxf(St[14], St[15])));
      mx = fmaxf(mx, mx2);
      mx = fmaxf(mx, __shfl_xor(mx, 32));
      bool upd = __any(mx > m_ + 8.f);
      if (upd) {
        float mn = fmaxf(m_, mx);
        float scl = exp2f(m_ - mn);
        m_ = mn;
        Z_ *= scl;
#pragma unroll
        for (int r = 0; r < 16; r++) {
          int qr = (r & 3) + 8 * (r >> 2) + 4 * hi;
          float sb = __uint_as_float(
              (unsigned)__builtin_amdgcn_ds_bpermute(qr * 4, (int)__float_as_uint(scl)));
#pragma unroll
          for (int dt = 0; dt < 8; dt++) O[dt][r] *= sb;
        }
      }
      float p[16];
#pragma unroll
      for (int r = 0; r < 16; r++) p[r] = exp2f(St[r] - m_);
      float rs = ((p[0] + p[1]) + (p[2] + p[3])) + ((p[4] + p[5]) + (p[6] + p[7])) +
                 (((p[8] + p[9]) + (p[10] + p[11])) + ((p[12] + p[13]) + (p[14] + p[15])));
      rs += __shfl_xor(rs, 32);
      Z_ += rs;

      // ---- P -> bf16 A-fragments (pack pairs + cross-half exchange) ----
      unsigned X[8];
#pragma unroll
      for (int i = 0; i < 8; i++)
        X[i] = (unsigned)cvt_bf(p[2 * i]) | ((unsigned)cvt_bf(p[2 * i + 1]) << 16);
      unsigned Y0 = (unsigned)__shfl_xor((int)X[0], 32);
      unsigned Y1 = (unsigned)__shfl_xor((int)X[1], 32);
      unsigned Y2 = (unsigned)__shfl_xor((int)X[2], 32);
      unsigned Y3 = (unsigned)__shfl_xor((int)X[3], 32);
      unsigned Y4 = (unsigned)__shfl_xor((int)X[4], 32);
      unsigned Y5 = (unsigned)__shfl_xor((int)X[5], 32);
      unsigned Y6 = (unsigned)__shfl_xor((int)X[6], 32);
      unsigned Y7 = (unsigned)__shfl_xor((int)X[7], 32);
      u32x4 A0, A1;
      A0[0] = hi ? Y2 : X[0]; A0[1] = hi ? Y3 : X[1];
      A0[2] = hi ? X[2] : Y0; A0[3] = hi ? X[3] : Y1;
      A1[0] = hi ? Y6 : X[4]; A1[1] = hi ? Y7 : X[5];
      A1[2] = hi ? X[6] : Y4; A1[3] = hi ? X[7] : Y5;
      bf16x8 pa0 = __builtin_bit_cast(bf16x8, A0);
      bf16x8 pa1 = __builtin_bit_cast(bf16x8, A1);

      // ---- PV: O[q][d] += P @ V ----
      __builtin_amdgcn_s_setprio(1);
#pragma unroll
      for (int dt = 0; dt < 8; dt++) {
        bf16x8 vf0 = *(const bf16x8*)(Vp + (dt * 32 + r32) * 64 + ((hi ^ vsw) * 16));
        O[dt] = __builtin_amdgcn_mfma_f32_32x32x16_bf16(pa0, vf0, O[dt], 0, 0, 0);
      }
#pragma unroll
      for (int dt = 0; dt < 8; dt++) {
        bf16x8 vf1 = *(const bf16x8*)(Vp + (dt * 32 + r32) * 64 + (((2 + hi) ^ vsw) * 16));
        O[dt] = __builtin_amdgcn_mfma_f32_32x32x16_bf16(pa1, vf1, O[dt], 0, 0, 0);
      }
      __builtin_amdgcn_s_setprio(0);
    }

    __builtin_amdgcn_sched_barrier(0);
    __builtin_amdgcn_s_barrier();
    if (kt + 2 < t1) STAGE(cur, kt + 2);
  }

  // ---- write partial stats + bf16 O ----
  int grow_base = b * 4096 + qwave;
  if (hi == 0) {
    float* mzm = mz + s * 32768;
    mzm[grow_base + r32] = m_;
    mzm[16384 + grow_base + r32] = Z_;
  }
#pragma unroll
  for (int r = 0; r < 16; r++) {
    int qr = (r & 3) + 8 * (r >> 2) + 4 * hi;
    size_t grow = (size_t)(grow_base + qr);
#pragma unroll
    for (int dt = 0; dt < 8; dt++) {
      int dcol = dt * 32 + r32;
      unsigned short vb = cvt_bf(O[dt][r]);
      if (s < 2)
        slot01[grow * 512 + (size_t)s * 256 + dcol] = vb;
      else if (s < 4)
        slot23[(size_t)(s - 2) * 4194304 + grow * 256 + dcol] = vb;
      else
        slot45[(size_t)(s - 4) * 4194304 + grow * 256 + dcol] = vb;
    }
  }
}

// ---------------- combine6: merge 6 partials + masked-zero correction + qp residual ----------------
__global__ __launch_bounds__(256) void combine6_kernel(
    const float* __restrict__ mz,
    const unsigned short* __restrict__ slot23, const unsigned short* __restrict__ slot45,
    const unsigned short* __restrict__ qpb, const unsigned short* __restrict__ suffv,
    float* __restrict__ out) {
  int grow = blockIdx.x * 4 + (threadIdx.x >> 6);
  int col = (threadIdx.x & 63) * 4;
  const unsigned short* slot01 = (const unsigned short*)out;

  float mv[6], Zv[6];
#pragma unroll
  for (int s = 0; s < 6; s++) {
    const float* mzm = mz + s * 32768;
    mv[s] = mzm[grow];
    Zv[s] = mzm[16384 + grow];
  }
  float M = mv[0];
#pragma unroll
  for (int s = 1; s < 6; s++) M = fmaxf(M, mv[s]);
  float fs[6], Zm = 0.f;
#pragma unroll
  for (int s = 0; s < 6; s++) {
    fs[s] = exp2f(mv[s] - M);
    Zm += Zv[s] * fs[s];
  }

  int q = grow & 4095;
  int nmask = 4095 - q;
  float scl, e0, Zf;
  if (nmask > 0) {
    float Mf = fmaxf(M, 0.f);  // log2-space: masked zeros contribute 2^(0 - Mf)
    scl = exp2f(M - Mf);
    e0 = exp2f(-Mf);
    Zf = Zm * scl + (float)nmask * e0;
  } else {
    scl = 1.f; e0 = 0.f; Zf = Zm;
  }
  float rZ = 1.f / Zf;
  float a[6];
#pragma unroll
  for (int s = 0; s < 6; s++) a[s] = fs[s] * scl * rZ;
  float asv = e0 * rZ;

  size_t base = (size_t)grow * 256 + col;
  uint2 ss[6];
  ss[0] = *(const uint2*)(slot01 + (size_t)grow * 512 + col);
  ss[1] = *(const uint2*)(slot01 + (size_t)grow * 512 + 256 + col);
  ss[2] = *(const uint2*)(slot23 + base);
  ss[3] = *(const uint2*)(slot23 + 4194304 + base);
  ss[4] = *(const uint2*)(slot45 + base);
  ss[5] = *(const uint2*)(slot45 + 4194304 + base);
  uint2 qpr = *(const uint2*)(qpb + base);
  uint2 svu = *(const uint2*)(suffv + base);

  __syncthreads();  // all slot01 (= out bytes) reads in this block complete before writes

  float4 res;
  res.x = 16.f * bf2f(qpr.x & 0xffff) + bf2f(svu.x & 0xffff) * asv;
  res.y = 16.f * bf2f(qpr.x >> 16) + bf2f(svu.x >> 16) * asv;
  res.z = 16.f * bf2f(qpr.y & 0xffff) + bf2f(svu.y & 0xffff) * asv;
  res.w = 16.f * bf2f(qpr.y >> 16) + bf2f(svu.y >> 16) * asv;
#pragma unroll
  for (int s = 0; s < 6; s++) {
    res.x += bf2f(ss[s].x & 0xffff) * a[s];
    res.y += bf2f(ss[s].x >> 16) * a[s];
    res.z += bf2f(ss[s].y & 0xffff) * a[s];
    res.w += bf2f(ss[s].y >> 16) * a[s];
  }
  *(float4*)&out[base] = res;
}

// ---------------- launch ----------------
// Workspace layout (disjoint; ~66 MiB, within proven bound):
//   [ 0,16M) slot45 | [16M,32M) slot23 | [32M,40M) suffv bf16 | [40M,48M) qpb
//   [48M,56M) kpb | [56M,64M) vptb [B][128][256][32] | [64M,+768K) mz | +384K WT | +512K ctot
extern "C" void kernel_launch(void* const* d_in, const int* in_sizes, int n_in,
                              void* d_out, int out_size, void* d_ws, size_t ws_size,
                              hipStream_t stream) {
  const float* v_in = (const float*)d_in[0];
  const float* k_in = (const float*)d_in[1];
  const float* q_in = (const float*)d_in[2];
  const float* Wq = (const float*)d_in[3];
  const float* bq = (const float*)d_in[4];
  const float* Wk = (const float*)d_in[5];
  const float* bk = (const float*)d_in[6];
  const float* Wv = (const float*)d_in[7];
  const float* bv = (const float*)d_in[8];
  float* out = (float*)d_out;

  char* p = (char*)d_ws;
  unsigned short* slot45 = (unsigned short*)(p + 0);
  unsigned short* slot23 = (unsigned short*)(p + 16777216);
  unsigned short* suffv = (unsigned short*)(p + 33554432);
  unsigned short* qpb = (unsigned short*)(p + 41943040);
  unsigned short* kpb = (unsigned short*)(p + 50331648);
  unsigned short* vptb = (unsigned short*)(p + 58720256);
  float* mz = (float*)(p + 67108864);
  unsigned short* WTq = (unsigned short*)(p + 67895296);
  unsigned short* WTk = (unsigned short*)(p + 68026368);
  unsigned short* WTv = (unsigned short*)(p + 68157440);
  float* ctot = (float*)(p + 68288512);                 // [4][128][256] f32 = 512 KB
  unsigned short* slot01 = (unsigned short*)d_out;

  hipFuncSetAttribute((const void*)attn14_kernel,
                      hipFuncAttributeMaxDynamicSharedMemorySize, 65536);

  wt_kernel<<<768, 256, 0, stream>>>(Wq, Wk, Wv, WTq, WTk, WTv);
  proj_all_kernel<<<dim3(256, 3), 256, 0, stream>>>(q_in, k_in, v_in, WTq, WTk, WTv,
                                                    bq, bk, bv, qpb, kpb, vptb);
  scan1<<<dim3(128, 4), 256, 0, stream>>>(vptb, ctot);
  scan2<<<dim3(128, 4), 256, 0, stream>>>(vptb, ctot, suffv);
  attn14_kernel<<<768, 256, 65536, stream>>>(qpb, kpb, vptb, slot01, slot23, slot45, mz);
  combine6_kernel<<<4096, 256, 0, stream>>>(mz, slot23, slot45, qpb, suffv, out);
}